// Round 8
// baseline (204.519 us; speedup 1.0000x reference)
//
#include <hip/hip_runtime.h>
#include <math.h>

typedef _Float16 f16;
typedef _Float16 f16x8 __attribute__((ext_vector_type(8)));
typedef float f32x4 __attribute__((ext_vector_type(4)));
typedef unsigned u32x2 __attribute__((ext_vector_type(2)));

#define B_  4
#define N_  2048
#define C_  128
#define NS_ 64

// ---- workspace layout (bytes) ----
#define WS_FEATNC 0u          // B*N*C f32 = 4194304
#define WS_IDX    4194304u    // B*N*NS u16 = 1048576
#define WS_W1P    5242880u    // 4 slices * 16384 = 65536
#define WS_W2P    5308416u    // 4 slices * 16384 = 65536

// ---- mlp LDS layout (bytes), total 67584 -> 2 x 512-thr blocks/CU ----
#define LDS_H    0            // h: 4 slots x 4096 = 16384 (a1 halves overlay; a2 f32 overlays H+W)
#define LDS_W    16384        // weight triple-buffer 3 x 16384 = 49152 (ends 65536)
#define LDS_GX   65536        // [64][3] f32 = 768
#define LDS_QF   66304        // [128] f32 = 512
#define LDS_IDX  66816        // 256 (RED overlays after gather)
#define LDS_RED  66816
#define LDS_W3   67072        // 512
#define LDS_TOTAL 67584

#define PHASE_BAR2() asm volatile("s_waitcnt vmcnt(2) lgkmcnt(0)\ns_barrier" ::: "memory")
#define PHASE_BAR0() asm volatile("s_waitcnt vmcnt(0) lgkmcnt(0)\ns_barrier" ::: "memory")
#define LBAR()       asm volatile("s_waitcnt lgkmcnt(0)\ns_barrier" ::: "memory")

__device__ __forceinline__ void gl_lds16(const char* gp, char* lp) {
  __builtin_amdgcn_global_load_lds(
      (const __attribute__((address_space(1))) unsigned int*)gp,
      (__attribute__((address_space(3))) unsigned int*)lp, 16, 0, 0);
}

// pack two floats as adjacent f16 (RTN)
__device__ __forceinline__ unsigned pk2(float a, float b) {
  union { f16 h[2]; unsigned u; } cv;
  cv.h[0] = (f16)a; cv.h[1] = (f16)b;
  return cv.u;
}

// ---------------------------------------------------------------------------
// prep: feat (B,C,N)->(B,N,C) f32; W1 feature-cols -> 4 K-slices (32 ch each)
// [256 o][16 ch-pair slots] f16 swizzled (row 64B); W2 -> 4 K-slices (64 ch)
// [128 p][32 pair slots] (row 128B). Images are exact LDS bytes for linear
// global_load_lds staging.
// ---------------------------------------------------------------------------
__global__ __launch_bounds__(256) void prep_kernel(
    const float* __restrict__ feat, const float* __restrict__ W1,
    const float* __restrict__ W2, float* __restrict__ feat_nc,
    char* __restrict__ W1p, char* __restrict__ W2p)
{
  int i = blockIdx.x * 256 + threadIdx.x;
  {
    int n = i & (N_ - 1);
    int bc = i >> 11;
    int c = bc & (C_ - 1);
    int b = bc >> 7;
    feat_nc[(size_t)((b << 11) + n) * C_ + c] = feat[i];
  }
  if (i < 16384) {   // W1: g = slice (32 ch), [o 0..255][j 0..15]; ch = 3+32g+2j
    int g = i >> 12, r = i & 4095, o = r >> 4, j = r & 15;
    const float* row = W1 + o * 131 + 3 + g * 32 + 2 * j;
    unsigned byte = ((unsigned)(o * 64 + j * 4)) ^ ((unsigned)(((o >> 1) & 7) << 4));
    *(unsigned*)(W1p + (size_t)g * 16384 + byte) = pk2(row[0], row[1]);
  }
  if (i < 16384) {   // W2: ko = slice (64 ch), [p 0..127][j 0..31]; o = 64ko+2j
    int ko = i >> 12, r = i & 4095, p = r >> 5, j = r & 31;
    int o = ko * 64 + 2 * j;
    unsigned byte = ((unsigned)(p * 128 + j * 4)) ^ ((unsigned)(((p >> 1) & 7) << 4));
    *(unsigned*)(W2p + (size_t)ko * 16384 + byte) = pk2(W2[p * 256 + o], W2[p * 256 + o + 1]);
  }
}

// ---------------------------------------------------------------------------
// ball query (fp64-exact membership), output u16
// ---------------------------------------------------------------------------
__global__ __launch_bounds__(256) void ballquery_kernel(
    const float* __restrict__ xyz, unsigned short* __restrict__ idxout)
{
  __shared__ float  xl[N_ * 3];
  __shared__ double sq[N_];
  __shared__ int    ibuf[4][NS_];

  const int b  = blockIdx.x >> 9;
  const int ng = blockIdx.x & 511;
  const int t  = threadIdx.x;
  const float* xb = xyz + (size_t)b * N_ * 3;

  for (int i = t; i < N_ * 3; i += 256) xl[i] = xb[i];
  __syncthreads();
  for (int i = t; i < N_; i += 256) {
    double x = (double)xl[3*i], y = (double)xl[3*i+1], z = (double)xl[3*i+2];
    sq[i] = x*x + y*y + z*z;
  }
  __syncthreads();

  const int wv = t >> 6, lane = t & 63;
  const int n = ng * 4 + wv;
  const double xn = (double)xl[3*n], yn = (double)xl[3*n+1], zn = (double)xl[3*n+2];
  const double sn = sq[n];

  int cnt = 0;
  for (int mb = 0; mb < N_; mb += 64) {
    int m = mb + lane;
    double dot = xn*(double)xl[3*m] + yn*(double)xl[3*m+1] + zn*(double)xl[3*m+2];
    double d2 = (sn + sq[m]) - 2.0 * dot;
    bool hit = d2 < 0.0625;
    unsigned long long mask = __ballot(hit);
    int pos = __popcll(mask & ((1ULL << lane) - 1ULL));
    int slot = cnt + pos;
    if (hit && slot < NS_) ibuf[wv][slot] = m;
    cnt += (int)__popcll(mask);
    if (cnt >= NS_) break;
  }
  asm volatile("s_waitcnt lgkmcnt(0)" ::: "memory");
  int total = cnt < NS_ ? cnt : NS_;
  int v = ibuf[wv][lane < total ? lane : 0];
  idxout[((size_t)b * N_ + n) * NS_ + lane] = (unsigned short)v;
}

// ---------------------------------------------------------------------------
// MLP: pure-f16 MFMA, 512-thread blocks (8 waves), 2 blocks/CU, no spill.
// 8 uniform phases (GEMM1 4 x K32, GEMM2 4 x K64), W triple-buffer with
// depth-2 counted-vmcnt prefetch (raw s_barrier + vmcnt(2), never drain).
// GEMM1: wave w owns o in [32w,32w+32) -> acc1[4][2]. GEMM2: wave w owns
// p in [16w,16w+16) -> acc2[4]. a1 half-split overlays h slots.
// FIX vs R7: GEMM2 bf1 k-offset (+64, bit 6) must be INSIDE the row-swizzle
// XOR (mask covers bits 4-6); outside-XOR read bytes were wrong for l15>=8.
// ---------------------------------------------------------------------------
__global__ __launch_bounds__(512, 4) void mlp_kernel(
    const float* __restrict__ xyz, const float* __restrict__ feat_nc,
    const char* __restrict__ w1p, const char* __restrict__ w2p,
    const unsigned short* __restrict__ idxg,
    const float* __restrict__ W1g, const float* __restrict__ W3g,
    const float* __restrict__ g1, const float* __restrict__ b1,
    const float* __restrict__ g2, const float* __restrict__ b2,
    const float* __restrict__ g3, const float* __restrict__ b3,
    float* __restrict__ out)
{
  __shared__ __attribute__((aligned(128))) char lds[LDS_TOTAL];

  const int bidRaw = blockIdx.x;
  const int bn = ((bidRaw & 7) << 10) + (bidRaw >> 3);   // XCD swizzle (bijective)
  const int b = bn >> 11;
  const int n = bn & (N_ - 1);
  const int t = threadIdx.x;
  const int w = t >> 6, lane = t & 63;
  const int l15 = lane & 15, lg = lane >> 4;
  const unsigned swzl = (unsigned)(((l15 >> 1) & 7) << 4);
  const unsigned labase = ((unsigned)(l15 * 64 + lg * 16)) ^ swzl;
  const unsigned w2b0 = ((unsigned)(l15 * 128 + lg * 16)) ^ swzl;        // k 0..31
  const unsigned w2b1 = ((unsigned)(l15 * 128 + 64 + lg * 16)) ^ swzl;   // k 32..63 (bit6 inside XOR)
  const float inv = 1.0f / sqrtf(1.0f + 1e-5f);

  float gg1v[2], bo1v[2], wx[2][3];
  #pragma unroll
  for (int nt2 = 0; nt2 < 2; ++nt2) {
    int o = 32 * w + nt2 * 16 + l15;
    gg1v[nt2] = g1[o] * inv; bo1v[nt2] = b1[o];
    #pragma unroll
    for (int c = 0; c < 3; ++c) wx[nt2][c] = W1g[o * 131 + c];
  }
  const int prow = 16 * w + l15;
  const float gg2 = g2[prow] * inv, bo2 = b2[prow];
  const float g3c = g3[0] * inv, b3c = b3[0];
  const float xn0 = xyz[(size_t)bn*3+0], xn1 = xyz[(size_t)bn*3+1], xn2 = xyz[(size_t)bn*3+2];

  auto STAGE = [&](int sl) {
    const char* gp = (sl < 4 ? w1p + (size_t)sl * 16384
                             : w2p + (size_t)(sl - 4) * 16384) + t * 16;
    char* lp = lds + LDS_W + (sl % 3) * 16384 + (w << 10);
    gl_lds16(gp, lp);
    gl_lds16(gp + 8192, lp + 8192);
  };

  // epilogue1: wave writes its 32 a1 channels into h slot (w&3), f16 swizzled
  f32x4 acc1[4][2];
  f32x4 acc2[4] = {};
  auto EPI1 = [&]() {
    const int slot = w & 3;
    #pragma unroll
    for (int mt = 0; mt < 4; ++mt)
      #pragma unroll
      for (int nt2 = 0; nt2 < 2; ++nt2)
        #pragma unroll
        for (int r = 0; r < 4; ++r) {
          int s = mt * 16 + lg * 4 + r;
          float a = fmaf(acc1[mt][nt2][r], gg1v[nt2], bo1v[nt2]);
          a = a > 0.0f ? a : 0.0f;
          unsigned byte = (unsigned)(slot * 4096)
            + (((unsigned)(s * 64 + (nt2 * 16 + l15) * 2)) ^ ((unsigned)(((s >> 1) & 7) << 4))
               ^ ((unsigned)(slot << 4)));
          *(f16*)(lds + LDS_H + byte) = (f16)a;
        }
  };

  // ---- prologue ----
  STAGE(0); STAGE(1);
  if (t < 64) ((int*)(lds + LDS_IDX))[t] = (int)idxg[(size_t)bn * 64 + t];
  if (t < 128) ((float*)(lds + LDS_QF))[t] = feat_nc[(size_t)bn * C_ + t];
  if (t < 128) ((float*)(lds + LDS_W3))[t] = W3g[t];
  LBAR();

  const int* idxl = (const int*)(lds + LDS_IDX);
  const float* qf = (const float*)(lds + LDS_QF);

  // gather features -> h f16 (4 channels per b64 write), 4 iters
  #pragma unroll
  for (int k = 0; k < 4; ++k) {
    int i = t + k * 512;
    int s = i >> 5, q4 = i & 31;
    int m = idxl[s];
    f32x4 f = *(const f32x4*)(feat_nc + ((size_t)b * N_ + m) * C_ + q4 * 4);
    int j4 = q4 * 4;
    float d0 = f[0] - qf[j4 + 0];
    float d1 = f[1] - qf[j4 + 1];
    float d2 = f[2] - qf[j4 + 2];
    float d3 = f[3] - qf[j4 + 3];
    int g = q4 >> 3;
    unsigned byte = (unsigned)(g * 4096)
      + (((unsigned)(s * 64 + (q4 & 7) * 8)) ^ ((unsigned)(((s >> 1) & 7) << 4))
         ^ ((unsigned)((g & 3) << 4)));
    u32x2 v;
    v.x = pk2(d0 * d0, d1 * d1);
    v.y = pk2(d2 * d2, d3 * d3);
    *(u32x2*)(lds + LDS_H + byte) = v;
  }
  // gather xyz -> GX (relative coords; also feeds VALU z1 contribution)
  if (t < 192) {
    int s = t & 63, c = t >> 6;
    int m = idxl[s];
    float p = xyz[((size_t)b * N_ + m) * 3 + c];
    float xnc = (c == 0) ? xn0 : (c == 1 ? xn1 : xn2);
    ((float*)(lds + LDS_GX))[s * 3 + c] = p - xnc;
  }
  LBAR();

  // ---- xyz-channel contribution: acc1 init on VALU ----
  {
    const float* gx = (const float*)(lds + LDS_GX);
    #pragma unroll
    for (int mt = 0; mt < 4; ++mt)
      #pragma unroll
      for (int r = 0; r < 4; ++r) {
        int s = mt * 16 + lg * 4 + r;
        float d0 = gx[s * 3 + 0] - xn0;
        float d1 = gx[s * 3 + 1] - xn1;
        float d2 = gx[s * 3 + 2] - xn2;
        d0 *= d0; d1 *= d1; d2 *= d2;
        #pragma unroll
        for (int nt2 = 0; nt2 < 2; ++nt2)
          acc1[mt][nt2][r] = fmaf(wx[nt2][0], d0, fmaf(wx[nt2][1], d1, wx[nt2][2] * d2));
      }
  }

  // ---- GEMM1: phases 0..3 (K=32 each) ----
  #pragma unroll
  for (int p = 0; p < 4; ++p) {
    STAGE(p + 2);                               // S2..S5
    const char* hb = lds + LDS_H + p * 4096;
    const unsigned gxr = ((unsigned)p) << 4;
    f16x8 af[4];
    #pragma unroll
    for (int mt = 0; mt < 4; ++mt)
      af[mt] = *(const f16x8*)(hb + mt * 1024 + (labase ^ gxr));
    const char* wb = lds + LDS_W + (p % 3) * 16384 + w * 2048;
    f16x8 bf0 = *(const f16x8*)(wb + labase);
    f16x8 bf1 = *(const f16x8*)(wb + 1024 + labase);
    __builtin_amdgcn_s_setprio(1);
    #pragma unroll
    for (int mt = 0; mt < 4; ++mt) {
      acc1[mt][0] = __builtin_amdgcn_mfma_f32_16x16x32_f16(af[mt], bf0, acc1[mt][0], 0, 0, 0);
      acc1[mt][1] = __builtin_amdgcn_mfma_f32_16x16x32_f16(af[mt], bf1, acc1[mt][1], 0, 0, 0);
    }
    __builtin_amdgcn_s_setprio(0);
    PHASE_BAR2();
  }

  // a1 half0 (o<128): waves 0..3
  if (w < 4) EPI1();
  LBAR();

  // ---- GEMM2: phases 4..7 (K=64 each) ----
  #pragma unroll
  for (int ko = 0; ko < 4; ++ko) {
    if (ko < 2) STAGE(6 + ko);                  // S6, S7
    const char* wb = lds + LDS_W + ((4 + ko) % 3) * 16384 + w * 2048;
    f16x8 bf0 = *(const f16x8*)(wb + w2b0);
    f16x8 bf1 = *(const f16x8*)(wb + w2b1);
    const int sl0 = (2 * ko) & 3, sl1 = (2 * ko + 1) & 3;
    f16x8 a0f[4], a1f[4];
    #pragma unroll
    for (int mt = 0; mt < 4; ++mt) {
      a0f[mt] = *(const f16x8*)(lds + LDS_H + sl0 * 4096 + mt * 1024 + (labase ^ (unsigned)(sl0 << 4)));
      a1f[mt] = *(const f16x8*)(lds + LDS_H + sl1 * 4096 + mt * 1024 + (labase ^ (unsigned)(sl1 << 4)));
    }
    __builtin_amdgcn_s_setprio(1);
    #pragma unroll
    for (int mt = 0; mt < 4; ++mt) {
      acc2[mt] = __builtin_amdgcn_mfma_f32_16x16x32_f16(a0f[mt], bf0, acc2[mt], 0, 0, 0);
      acc2[mt] = __builtin_amdgcn_mfma_f32_16x16x32_f16(a1f[mt], bf1, acc2[mt], 0, 0, 0);
    }
    __builtin_amdgcn_s_setprio(0);
    if (ko == 0) {
      PHASE_BAR2();
    } else if (ko == 1) {
      PHASE_BAR2();
      if (w >= 4) EPI1();                       // a1 half1 (o>=128) into slots 0..3
      LBAR();
    } else if (ko == 2) {
      PHASE_BAR0();
    } else {
      LBAR();                                   // before a2 overlay writes
    }
  }

  // ---- epilogue2: a2 = relu(bn2(z2)) f32, rows stride 528B (overlays H+W) ----
  #pragma unroll
  for (int mt = 0; mt < 4; ++mt)
    #pragma unroll
    for (int r = 0; r < 4; ++r) {
      int s = mt * 16 + lg * 4 + r;
      float a = fmaf(acc2[mt][r], gg2, bo2);
      a = a > 0.0f ? a : 0.0f;
      *(float*)(lds + s * 528 + prow * 4) = a;
    }
  LBAR();

  // ---- GEMM3 + weighted mean ----
  {
    int s3 = t >> 3, q3 = t & 7;                // 8 threads per sample
    const float* a2row = (const float*)lds + s3 * 132;
    const float* w3r = (const float*)(lds + LDS_W3);
    float z3 = 0.0f;
    #pragma unroll
    for (int i = 0; i < 4; ++i) {
      f32x4 av = *(const f32x4*)(a2row + q3 * 16 + i * 4);
      f32x4 wv = *(const f32x4*)(w3r + q3 * 16 + i * 4);
      z3 = fmaf(av[0], wv[0], z3); z3 = fmaf(av[1], wv[1], z3);
      z3 = fmaf(av[2], wv[2], z3); z3 = fmaf(av[3], wv[3], z3);
    }
    z3 += __shfl_xor(z3, 1);
    z3 += __shfl_xor(z3, 2);
    z3 += __shfl_xor(z3, 4);
    float wgt = fmaf(g3c, z3, b3c);
    wgt = wgt > 0.0f ? wgt : 0.0f;
    float v0 = 0.f, v1 = 0.f, v2 = 0.f, v3 = 0.f;
    if (q3 == 0) {
      const float* gx = (const float*)(lds + LDS_GX) + s3 * 3;
      v0 = gx[0] * wgt; v1 = gx[1] * wgt; v2 = gx[2] * wgt; v3 = wgt;
    }
    #pragma unroll
    for (int off = 8; off < 64; off <<= 1) {
      v0 += __shfl_xor(v0, off); v1 += __shfl_xor(v1, off);
      v2 += __shfl_xor(v2, off); v3 += __shfl_xor(v3, off);
    }
    if (lane == 0) {
      float* red = (float*)(lds + LDS_RED);
      red[w * 4 + 0] = v0; red[w * 4 + 1] = v1;
      red[w * 4 + 2] = v2; red[w * 4 + 3] = v3;
    }
    LBAR();
    if (t == 0) {
      const float* red = (const float*)(lds + LDS_RED);
      float n0 = 0.f, n1 = 0.f, n2 = 0.f, dd = 0.f;
      #pragma unroll
      for (int i = 0; i < 8; ++i) {
        n0 += red[i * 4 + 0]; n1 += red[i * 4 + 1];
        n2 += red[i * 4 + 2]; dd += red[i * 4 + 3];
      }
      out[(size_t)(b * 3 + 0) * N_ + n] = n0 / dd;
      out[(size_t)(b * 3 + 1) * N_ + n] = n1 / dd;
      out[(size_t)(b * 3 + 2) * N_ + n] = n2 / dd;
    }
  }
}

extern "C" void kernel_launch(void* const* d_in, const int* in_sizes, int n_in,
                              void* d_out, int out_size, void* d_ws, size_t ws_size,
                              hipStream_t stream) {
  (void)in_sizes; (void)n_in; (void)out_size; (void)ws_size;
  const float* xyz      = (const float*)d_in[0];
  const float* features = (const float*)d_in[1];
  const float* W1 = (const float*)d_in[2];
  const float* W2 = (const float*)d_in[3];
  const float* W3 = (const float*)d_in[4];
  const float* g1 = (const float*)d_in[5];
  const float* g2 = (const float*)d_in[6];
  const float* g3 = (const float*)d_in[7];
  const float* b1 = (const float*)d_in[8];
  const float* b2 = (const float*)d_in[9];
  const float* b3 = (const float*)d_in[10];
  float* out = (float*)d_out;

  char* ws = (char*)d_ws;
  float* feat_nc      = (float*)(ws + WS_FEATNC);
  unsigned short* idx = (unsigned short*)(ws + WS_IDX);
  char* W1p           = ws + WS_W1P;
  char* W2p           = ws + WS_W2P;

  prep_kernel<<<dim3((B_ * C_ * N_) / 256), dim3(256), 0, stream>>>(
      features, W1, W2, feat_nc, W1p, W2p);
  ballquery_kernel<<<dim3(B_ * N_ / 4), dim3(256), 0, stream>>>(xyz, idx);
  mlp_kernel<<<dim3(B_ * N_), dim3(512), 0, stream>>>(
      xyz, feat_nc, W1p, W2p, idx, W1, W3, g1, b1, g2, b2, g3, b3, out);
}

// Round 9
// 204.330 us; speedup vs baseline: 1.0009x; 1.0009x over previous
//
#include <hip/hip_runtime.h>
#include <math.h>

typedef _Float16 f16;
typedef _Float16 f16x8 __attribute__((ext_vector_type(8)));
typedef float f32x4 __attribute__((ext_vector_type(4)));
typedef unsigned u32x2 __attribute__((ext_vector_type(2)));

#define B_  4
#define N_  2048
#define C_  128
#define NS_ 64

// ---- workspace layout (bytes) ----
#define WS_FEATNC 0u          // B*N*C f32 = 4194304
#define WS_IDX    4194304u    // B*N*NS u16 = 1048576
#define WS_W1P    5242880u    // 4 slices * 16384 = 65536
#define WS_W2P    5308416u    // 4 slices * 16384 = 65536

// ---- mlp LDS layout (bytes), total 67584 -> 2 x 512-thr blocks/CU ----
#define LDS_H    0            // h: 4 slots x 4096 = 16384 (a1 halves overlay; a2 f32 overlays H+W)
#define LDS_W    16384        // weight triple-buffer 3 x 16384 = 49152 (ends 65536)
#define LDS_GX   65536        // [64][3] f32 = 768
#define LDS_QF   66304        // [128] f32 = 512
#define LDS_IDX  66816        // 256 (RED overlays after gather)
#define LDS_RED  66816
#define LDS_W3   67072        // 512
#define LDS_TOTAL 67584

#define PHASE_BAR2() asm volatile("s_waitcnt vmcnt(2) lgkmcnt(0)\ns_barrier" ::: "memory")
#define PHASE_BAR0() asm volatile("s_waitcnt vmcnt(0) lgkmcnt(0)\ns_barrier" ::: "memory")
#define LBAR()       asm volatile("s_waitcnt lgkmcnt(0)\ns_barrier" ::: "memory")

__device__ __forceinline__ void gl_lds16(const char* gp, char* lp) {
  __builtin_amdgcn_global_load_lds(
      (const __attribute__((address_space(1))) unsigned int*)gp,
      (__attribute__((address_space(3))) unsigned int*)lp, 16, 0, 0);
}

// pack two floats as adjacent f16 (RTN)
__device__ __forceinline__ unsigned pk2(float a, float b) {
  union { f16 h[2]; unsigned u; } cv;
  cv.h[0] = (f16)a; cv.h[1] = (f16)b;
  return cv.u;
}

// ---------------------------------------------------------------------------
// prep: feat (B,C,N)->(B,N,C) f32; W1 feature-cols -> 4 K-slices (32 ch each)
// [256 o][16 ch-pair slots] f16 swizzled (row 64B); W2 -> 4 K-slices (64 ch)
// [128 p][32 pair slots] (row 128B). Images are exact LDS bytes for linear
// global_load_lds staging.
// ---------------------------------------------------------------------------
__global__ __launch_bounds__(256) void prep_kernel(
    const float* __restrict__ feat, const float* __restrict__ W1,
    const float* __restrict__ W2, float* __restrict__ feat_nc,
    char* __restrict__ W1p, char* __restrict__ W2p)
{
  int i = blockIdx.x * 256 + threadIdx.x;
  {
    int n = i & (N_ - 1);
    int bc = i >> 11;
    int c = bc & (C_ - 1);
    int b = bc >> 7;
    feat_nc[(size_t)((b << 11) + n) * C_ + c] = feat[i];
  }
  if (i < 16384) {   // W1: g = slice (32 ch), [o 0..255][j 0..15]; ch = 3+32g+2j
    int g = i >> 12, r = i & 4095, o = r >> 4, j = r & 15;
    const float* row = W1 + o * 131 + 3 + g * 32 + 2 * j;
    unsigned byte = ((unsigned)(o * 64 + j * 4)) ^ ((unsigned)(((o >> 1) & 7) << 4));
    *(unsigned*)(W1p + (size_t)g * 16384 + byte) = pk2(row[0], row[1]);
  }
  if (i < 16384) {   // W2: ko = slice (64 ch), [p 0..127][j 0..31]; o = 64ko+2j
    int ko = i >> 12, r = i & 4095, p = r >> 5, j = r & 31;
    int o = ko * 64 + 2 * j;
    unsigned byte = ((unsigned)(p * 128 + j * 4)) ^ ((unsigned)(((p >> 1) & 7) << 4));
    *(unsigned*)(W2p + (size_t)ko * 16384 + byte) = pk2(W2[p * 256 + o], W2[p * 256 + o + 1]);
  }
}

// ---------------------------------------------------------------------------
// ball query (fp64-exact membership), output u16
// ---------------------------------------------------------------------------
__global__ __launch_bounds__(256) void ballquery_kernel(
    const float* __restrict__ xyz, unsigned short* __restrict__ idxout)
{
  __shared__ float  xl[N_ * 3];
  __shared__ double sq[N_];
  __shared__ int    ibuf[4][NS_];

  const int b  = blockIdx.x >> 9;
  const int ng = blockIdx.x & 511;
  const int t  = threadIdx.x;
  const float* xb = xyz + (size_t)b * N_ * 3;

  for (int i = t; i < N_ * 3; i += 256) xl[i] = xb[i];
  __syncthreads();
  for (int i = t; i < N_; i += 256) {
    double x = (double)xl[3*i], y = (double)xl[3*i+1], z = (double)xl[3*i+2];
    sq[i] = x*x + y*y + z*z;
  }
  __syncthreads();

  const int wv = t >> 6, lane = t & 63;
  const int n = ng * 4 + wv;
  const double xn = (double)xl[3*n], yn = (double)xl[3*n+1], zn = (double)xl[3*n+2];
  const double sn = sq[n];

  int cnt = 0;
  for (int mb = 0; mb < N_; mb += 64) {
    int m = mb + lane;
    double dot = xn*(double)xl[3*m] + yn*(double)xl[3*m+1] + zn*(double)xl[3*m+2];
    double d2 = (sn + sq[m]) - 2.0 * dot;
    bool hit = d2 < 0.0625;
    unsigned long long mask = __ballot(hit);
    int pos = __popcll(mask & ((1ULL << lane) - 1ULL));
    int slot = cnt + pos;
    if (hit && slot < NS_) ibuf[wv][slot] = m;
    cnt += (int)__popcll(mask);
    if (cnt >= NS_) break;
  }
  asm volatile("s_waitcnt lgkmcnt(0)" ::: "memory");
  int total = cnt < NS_ ? cnt : NS_;
  int v = ibuf[wv][lane < total ? lane : 0];
  idxout[((size_t)b * N_ + n) * NS_ + lane] = (unsigned short)v;
}

// ---------------------------------------------------------------------------
// MLP: pure-f16 MFMA, 512-thread blocks (8 waves), 2 blocks/CU.
// waves_per_eu(4,4) pins the allocator at 4 waves/EU -> 128-VGPR budget ->
// no spill (R6/R8 pathology: min-only bound let the allocator target 8
// waves/EU = 64 VGPRs and spill 200-425MB to scratch).
// 8 uniform phases (GEMM1 4 x K32, GEMM2 4 x K64), W triple-buffer with
// depth-2 counted-vmcnt prefetch (raw s_barrier + vmcnt(2), never drain).
// GEMM1: wave w owns o in [32w,32w+32) -> acc1[4][2]. GEMM2: wave w owns
// p in [16w,16w+16) -> acc2[4]. a1 half-split overlays h slots.
// ---------------------------------------------------------------------------
__global__ __attribute__((amdgpu_waves_per_eu(4, 4))) __launch_bounds__(512)
void mlp_kernel(
    const float* __restrict__ xyz, const float* __restrict__ feat_nc,
    const char* __restrict__ w1p, const char* __restrict__ w2p,
    const unsigned short* __restrict__ idxg,
    const float* __restrict__ W1g, const float* __restrict__ W3g,
    const float* __restrict__ g1, const float* __restrict__ b1,
    const float* __restrict__ g2, const float* __restrict__ b2,
    const float* __restrict__ g3, const float* __restrict__ b3,
    float* __restrict__ out)
{
  __shared__ __attribute__((aligned(128))) char lds[LDS_TOTAL];

  const int bidRaw = blockIdx.x;
  const int bn = ((bidRaw & 7) << 10) + (bidRaw >> 3);   // XCD swizzle (bijective)
  const int b = bn >> 11;
  const int n = bn & (N_ - 1);
  const int t = threadIdx.x;
  const int w = t >> 6, lane = t & 63;
  const int l15 = lane & 15, lg = lane >> 4;
  const unsigned swzl = (unsigned)(((l15 >> 1) & 7) << 4);
  const unsigned labase = ((unsigned)(l15 * 64 + lg * 16)) ^ swzl;
  const unsigned w2b0 = ((unsigned)(l15 * 128 + lg * 16)) ^ swzl;        // k 0..31
  const unsigned w2b1 = ((unsigned)(l15 * 128 + 64 + lg * 16)) ^ swzl;   // k 32..63 (bit6 inside XOR)
  const float inv = 1.0f / sqrtf(1.0f + 1e-5f);

  float gg1v[2], bo1v[2], wx[2][3];
  #pragma unroll
  for (int nt2 = 0; nt2 < 2; ++nt2) {
    int o = 32 * w + nt2 * 16 + l15;
    gg1v[nt2] = g1[o] * inv; bo1v[nt2] = b1[o];
    #pragma unroll
    for (int c = 0; c < 3; ++c) wx[nt2][c] = W1g[o * 131 + c];
  }
  const int prow = 16 * w + l15;
  const float gg2 = g2[prow] * inv, bo2 = b2[prow];
  const float g3c = g3[0] * inv, b3c = b3[0];
  const float xn0 = xyz[(size_t)bn*3+0], xn1 = xyz[(size_t)bn*3+1], xn2 = xyz[(size_t)bn*3+2];

  auto STAGE = [&](int sl) {
    const char* gp = (sl < 4 ? w1p + (size_t)sl * 16384
                             : w2p + (size_t)(sl - 4) * 16384) + t * 16;
    char* lp = lds + LDS_W + (sl % 3) * 16384 + (w << 10);
    gl_lds16(gp, lp);
    gl_lds16(gp + 8192, lp + 8192);
  };

  // epilogue1: wave writes its 32 a1 channels into h slot (w&3), f16 swizzled
  f32x4 acc1[4][2];
  f32x4 acc2[4] = {};
  auto EPI1 = [&]() {
    const int slot = w & 3;
    #pragma unroll
    for (int mt = 0; mt < 4; ++mt)
      #pragma unroll
      for (int nt2 = 0; nt2 < 2; ++nt2)
        #pragma unroll
        for (int r = 0; r < 4; ++r) {
          int s = mt * 16 + lg * 4 + r;
          float a = fmaf(acc1[mt][nt2][r], gg1v[nt2], bo1v[nt2]);
          a = a > 0.0f ? a : 0.0f;
          unsigned byte = (unsigned)(slot * 4096)
            + (((unsigned)(s * 64 + (nt2 * 16 + l15) * 2)) ^ ((unsigned)(((s >> 1) & 7) << 4))
               ^ ((unsigned)(slot << 4)));
          *(f16*)(lds + LDS_H + byte) = (f16)a;
        }
  };

  // ---- prologue ----
  STAGE(0); STAGE(1);
  if (t < 64) ((int*)(lds + LDS_IDX))[t] = (int)idxg[(size_t)bn * 64 + t];
  if (t < 128) ((float*)(lds + LDS_QF))[t] = feat_nc[(size_t)bn * C_ + t];
  if (t < 128) ((float*)(lds + LDS_W3))[t] = W3g[t];
  LBAR();

  const int* idxl = (const int*)(lds + LDS_IDX);
  const float* qf = (const float*)(lds + LDS_QF);

  // gather features -> h f16 (4 channels per b64 write), 4 iters
  #pragma unroll
  for (int k = 0; k < 4; ++k) {
    int i = t + k * 512;
    int s = i >> 5, q4 = i & 31;
    int m = idxl[s];
    f32x4 f = *(const f32x4*)(feat_nc + ((size_t)b * N_ + m) * C_ + q4 * 4);
    int j4 = q4 * 4;
    float d0 = f[0] - qf[j4 + 0];
    float d1 = f[1] - qf[j4 + 1];
    float d2 = f[2] - qf[j4 + 2];
    float d3 = f[3] - qf[j4 + 3];
    int g = q4 >> 3;
    unsigned byte = (unsigned)(g * 4096)
      + (((unsigned)(s * 64 + (q4 & 7) * 8)) ^ ((unsigned)(((s >> 1) & 7) << 4))
         ^ ((unsigned)((g & 3) << 4)));
    u32x2 v;
    v.x = pk2(d0 * d0, d1 * d1);
    v.y = pk2(d2 * d2, d3 * d3);
    *(u32x2*)(lds + LDS_H + byte) = v;
  }
  // gather xyz -> GX (relative coords; also feeds VALU z1 contribution)
  if (t < 192) {
    int s = t & 63, c = t >> 6;
    int m = idxl[s];
    float p = xyz[((size_t)b * N_ + m) * 3 + c];
    float xnc = (c == 0) ? xn0 : (c == 1 ? xn1 : xn2);
    ((float*)(lds + LDS_GX))[s * 3 + c] = p - xnc;
  }
  LBAR();

  // ---- xyz-channel contribution: acc1 init on VALU ----
  {
    const float* gx = (const float*)(lds + LDS_GX);
    #pragma unroll
    for (int mt = 0; mt < 4; ++mt)
      #pragma unroll
      for (int r = 0; r < 4; ++r) {
        int s = mt * 16 + lg * 4 + r;
        float d0 = gx[s * 3 + 0] - xn0;
        float d1 = gx[s * 3 + 1] - xn1;
        float d2 = gx[s * 3 + 2] - xn2;
        d0 *= d0; d1 *= d1; d2 *= d2;
        #pragma unroll
        for (int nt2 = 0; nt2 < 2; ++nt2)
          acc1[mt][nt2][r] = fmaf(wx[nt2][0], d0, fmaf(wx[nt2][1], d1, wx[nt2][2] * d2));
      }
  }

  // ---- GEMM1: phases 0..3 (K=32 each) ----
  #pragma unroll
  for (int p = 0; p < 4; ++p) {
    STAGE(p + 2);                               // S2..S5
    const char* hb = lds + LDS_H + p * 4096;
    const unsigned gxr = ((unsigned)p) << 4;
    f16x8 af[4];
    #pragma unroll
    for (int mt = 0; mt < 4; ++mt)
      af[mt] = *(const f16x8*)(hb + mt * 1024 + (labase ^ gxr));
    const char* wb = lds + LDS_W + (p % 3) * 16384 + w * 2048;
    f16x8 bf0 = *(const f16x8*)(wb + labase);
    f16x8 bf1 = *(const f16x8*)(wb + 1024 + labase);
    __builtin_amdgcn_s_setprio(1);
    #pragma unroll
    for (int mt = 0; mt < 4; ++mt) {
      acc1[mt][0] = __builtin_amdgcn_mfma_f32_16x16x32_f16(af[mt], bf0, acc1[mt][0], 0, 0, 0);
      acc1[mt][1] = __builtin_amdgcn_mfma_f32_16x16x32_f16(af[mt], bf1, acc1[mt][1], 0, 0, 0);
    }
    __builtin_amdgcn_s_setprio(0);
    PHASE_BAR2();
  }

  // a1 half0 (o<128): waves 0..3
  if (w < 4) EPI1();
  LBAR();

  // ---- GEMM2: phases 4..7 (K=64 each) ----
  #pragma unroll
  for (int ko = 0; ko < 4; ++ko) {
    if (ko < 2) STAGE(6 + ko);                  // S6, S7
    const char* wb = lds + LDS_W + ((4 + ko) % 3) * 16384 + w * 2048;
    f16x8 bf0 = *(const f16x8*)(wb + w2b0);
    f16x8 bf1 = *(const f16x8*)(wb + w2b1);
    const int sl0 = (2 * ko) & 3, sl1 = (2 * ko + 1) & 3;
    f16x8 a0f[4], a1f[4];
    #pragma unroll
    for (int mt = 0; mt < 4; ++mt) {
      a0f[mt] = *(const f16x8*)(lds + LDS_H + sl0 * 4096 + mt * 1024 + (labase ^ (unsigned)(sl0 << 4)));
      a1f[mt] = *(const f16x8*)(lds + LDS_H + sl1 * 4096 + mt * 1024 + (labase ^ (unsigned)(sl1 << 4)));
    }
    __builtin_amdgcn_s_setprio(1);
    #pragma unroll
    for (int mt = 0; mt < 4; ++mt) {
      acc2[mt] = __builtin_amdgcn_mfma_f32_16x16x32_f16(a0f[mt], bf0, acc2[mt], 0, 0, 0);
      acc2[mt] = __builtin_amdgcn_mfma_f32_16x16x32_f16(a1f[mt], bf1, acc2[mt], 0, 0, 0);
    }
    __builtin_amdgcn_s_setprio(0);
    if (ko == 0) {
      PHASE_BAR2();
    } else if (ko == 1) {
      PHASE_BAR2();
      if (w >= 4) EPI1();                       // a1 half1 (o>=128) into slots 0..3
      LBAR();
    } else if (ko == 2) {
      PHASE_BAR0();
    } else {
      LBAR();                                   // before a2 overlay writes
    }
  }

  // ---- epilogue2: a2 = relu(bn2(z2)) f32, rows stride 528B (overlays H+W) ----
  #pragma unroll
  for (int mt = 0; mt < 4; ++mt)
    #pragma unroll
    for (int r = 0; r < 4; ++r) {
      int s = mt * 16 + lg * 4 + r;
      float a = fmaf(acc2[mt][r], gg2, bo2);
      a = a > 0.0f ? a : 0.0f;
      *(float*)(lds + s * 528 + prow * 4) = a;
    }
  LBAR();

  // ---- GEMM3 + weighted mean ----
  {
    int s3 = t >> 3, q3 = t & 7;                // 8 threads per sample
    const float* a2row = (const float*)lds + s3 * 132;
    const float* w3r = (const float*)(lds + LDS_W3);
    float z3 = 0.0f;
    #pragma unroll
    for (int i = 0; i < 4; ++i) {
      f32x4 av = *(const f32x4*)(a2row + q3 * 16 + i * 4);
      f32x4 wv = *(const f32x4*)(w3r + q3 * 16 + i * 4);
      z3 = fmaf(av[0], wv[0], z3); z3 = fmaf(av[1], wv[1], z3);
      z3 = fmaf(av[2], wv[2], z3); z3 = fmaf(av[3], wv[3], z3);
    }
    z3 += __shfl_xor(z3, 1);
    z3 += __shfl_xor(z3, 2);
    z3 += __shfl_xor(z3, 4);
    float wgt = fmaf(g3c, z3, b3c);
    wgt = wgt > 0.0f ? wgt : 0.0f;
    float v0 = 0.f, v1 = 0.f, v2 = 0.f, v3 = 0.f;
    if (q3 == 0) {
      const float* gx = (const float*)(lds + LDS_GX) + s3 * 3;
      v0 = gx[0] * wgt; v1 = gx[1] * wgt; v2 = gx[2] * wgt; v3 = wgt;
    }
    #pragma unroll
    for (int off = 8; off < 64; off <<= 1) {
      v0 += __shfl_xor(v0, off); v1 += __shfl_xor(v1, off);
      v2 += __shfl_xor(v2, off); v3 += __shfl_xor(v3, off);
    }
    if (lane == 0) {
      float* red = (float*)(lds + LDS_RED);
      red[w * 4 + 0] = v0; red[w * 4 + 1] = v1;
      red[w * 4 + 2] = v2; red[w * 4 + 3] = v3;
    }
    LBAR();
    if (t == 0) {
      const float* red = (const float*)(lds + LDS_RED);
      float n0 = 0.f, n1 = 0.f, n2 = 0.f, dd = 0.f;
      #pragma unroll
      for (int i = 0; i < 8; ++i) {
        n0 += red[i * 4 + 0]; n1 += red[i * 4 + 1];
        n2 += red[i * 4 + 2]; dd += red[i * 4 + 3];
      }
      out[(size_t)(b * 3 + 0) * N_ + n] = n0 / dd;
      out[(size_t)(b * 3 + 1) * N_ + n] = n1 / dd;
      out[(size_t)(b * 3 + 2) * N_ + n] = n2 / dd;
    }
  }
}

extern "C" void kernel_launch(void* const* d_in, const int* in_sizes, int n_in,
                              void* d_out, int out_size, void* d_ws, size_t ws_size,
                              hipStream_t stream) {
  (void)in_sizes; (void)n_in; (void)out_size; (void)ws_size;
  const float* xyz      = (const float*)d_in[0];
  const float* features = (const float*)d_in[1];
  const float* W1 = (const float*)d_in[2];
  const float* W2 = (const float*)d_in[3];
  const float* W3 = (const float*)d_in[4];
  const float* g1 = (const float*)d_in[5];
  const float* g2 = (const float*)d_in[6];
  const float* g3 = (const float*)d_in[7];
  const float* b1 = (const float*)d_in[8];
  const float* b2 = (const float*)d_in[9];
  const float* b3 = (const float*)d_in[10];
  float* out = (float*)d_out;

  char* ws = (char*)d_ws;
  float* feat_nc      = (float*)(ws + WS_FEATNC);
  unsigned short* idx = (unsigned short*)(ws + WS_IDX);
  char* W1p           = ws + WS_W1P;
  char* W2p           = ws + WS_W2P;

  prep_kernel<<<dim3((B_ * C_ * N_) / 256), dim3(256), 0, stream>>>(
      features, W1, W2, feat_nc, W1p, W2p);
  ballquery_kernel<<<dim3(B_ * N_ / 4), dim3(256), 0, stream>>>(xyz, idx);
  mlp_kernel<<<dim3(B_ * N_), dim3(512), 0, stream>>>(
      xyz, feat_nc, W1p, W2p, idx, W1, W3, g1, b1, g2, b2, g3, b3, out);
}